// Round 1
// baseline (1590.496 us; speedup 1.0000x reference)
//
#include <hip/hip_runtime.h>
#include <cstdint>
#include <cstddef>

#define D_DIM 256
#define T_DIM 512
#define B_DIM 128
#define S_DIM 512

typedef __attribute__((ext_vector_type(8))) short short8;
typedef __attribute__((ext_vector_type(4))) float f32x4;

// ---------- fp32 tiled GEMM (unchanged): C[M,N] = A @ B^T (+biases) ----------
__global__ __launch_bounds__(256, 2)
void gemm_bt(const float* __restrict__ A, const float* __restrict__ Bm,
             float* __restrict__ C,
             const float* __restrict__ bias1, const float* __restrict__ bias2,
             const int* __restrict__ ids, const float* __restrict__ emb,
             int M, int N, int K)
{
    __shared__ float As[16][128];
    __shared__ float Bs[16][128];
    const int tid = threadIdx.x;
    const int m0 = blockIdx.x * 128;
    const int n0 = blockIdx.y * 128;
    const int tx = tid & 15;
    const int ty = tid >> 4;

    float acc[8][8];
#pragma unroll
    for (int i = 0; i < 8; ++i)
#pragma unroll
        for (int j = 0; j < 8; ++j) acc[i][j] = 0.0f;

    for (int kc = 0; kc < K; kc += 16) {
#pragma unroll
        for (int p = 0; p < 2; ++p) {
            int f   = tid + p * 256;
            int row = f >> 2;
            int kq  = f & 3;
            int gm = m0 + row;
            const float* arow = ids ? (emb + (size_t)ids[gm] * K)
                                    : (A + (size_t)gm * K);
            float4 v = *(const float4*)(arow + kc + kq * 4);
            As[kq * 4 + 0][row] = v.x;
            As[kq * 4 + 1][row] = v.y;
            As[kq * 4 + 2][row] = v.z;
            As[kq * 4 + 3][row] = v.w;
            const float* brow = Bm + (size_t)(n0 + row) * K;
            float4 w = *(const float4*)(brow + kc + kq * 4);
            Bs[kq * 4 + 0][row] = w.x;
            Bs[kq * 4 + 1][row] = w.y;
            Bs[kq * 4 + 2][row] = w.z;
            Bs[kq * 4 + 3][row] = w.w;
        }
        __syncthreads();
#pragma unroll
        for (int k = 0; k < 16; ++k) {
            float a[8], b[8];
            *(float4*)&a[0] = *(const float4*)&As[k][ty * 8];
            *(float4*)&a[4] = *(const float4*)&As[k][ty * 8 + 4];
            *(float4*)&b[0] = *(const float4*)&Bs[k][tx * 8];
            *(float4*)&b[4] = *(const float4*)&Bs[k][tx * 8 + 4];
#pragma unroll
            for (int i = 0; i < 8; ++i)
#pragma unroll
                for (int j = 0; j < 8; ++j) acc[i][j] += a[i] * b[j];
        }
        __syncthreads();
    }

    float bv[8];
#pragma unroll
    for (int j = 0; j < 8; ++j) {
        int gn = n0 + tx * 8 + j;
        float v = 0.0f;
        if (bias1) v += bias1[gn];
        if (bias2) v += bias2[gn];
        bv[j] = v;
    }
#pragma unroll
    for (int i = 0; i < 8; ++i) {
        int gm = m0 + ty * 8 + i;
        float* crow = C + (size_t)gm * N + n0 + tx * 8;
        float4 v0 = make_float4(acc[i][0] + bv[0], acc[i][1] + bv[1],
                                acc[i][2] + bv[2], acc[i][3] + bv[3]);
        float4 v1 = make_float4(acc[i][4] + bv[4], acc[i][5] + bv[5],
                                acc[i][6] + bv[6], acc[i][7] + bv[7]);
        *(float4*)(crow)     = v0;
        *(float4*)(crow + 4) = v1;
    }
}

// ---------- helpers ----------
__device__ inline unsigned short f2bf(float x) {
    unsigned u = __builtin_bit_cast(unsigned, x);
    unsigned r = (u + 0x7fffu + ((u >> 16) & 1u)) >> 16;
    return (unsigned short)r;
}
__device__ inline float bf2f(unsigned short b) {
    unsigned u = ((unsigned)b) << 16;
    return __builtin_bit_cast(float, u);
}
__device__ inline float fast_tanh(float x) {
    float ax = __builtin_fabsf(x);
    float e  = __expf(-2.0f * ax);
    float r  = (1.0f - e) * __builtin_amdgcn_rcpf(1.0f + e);
    return __builtin_copysignf(r, x);
}

// LDS-only barrier: __syncthreads() lowers to s_waitcnt vmcnt(0) expcnt(0)
// lgkmcnt(0) + s_barrier, which drags the hout global-store retire and the
// HBM pre-prefetch latency onto the 512-iteration serial path every step.
// Only the LDS h-write -> h-read dependency actually needs the barrier.
__device__ inline void lds_barrier() {
    asm volatile("s_waitcnt lgkmcnt(0)" ::: "memory");
    __builtin_amdgcn_s_barrier();
    __builtin_amdgcn_sched_barrier(0);   // keep post-barrier ds_reads after it
}

// ---------- MFMA Elman scan, one batch row per block ----------
// 128 blocks x 1 batch row; 8 waves x 32 units; W_hh hi/lo bf16 fragments
// resident in regs.  A-fragment rows m=1..15 read a shared LDS zero region
// offset by 4 banks.  3-product split (hh + lh + hl), 6 independent chains.
// One LDS-only barrier/step; pre prefetched 2 steps ahead so the compiler's
// counted vmcnt wait before use is already satisfied; hout stores stay in
// flight across steps (never drained in-loop).
__global__ __launch_bounds__(512) __attribute__((amdgpu_waves_per_eu(2, 2)))
void rnn_scan_mfma(const float* __restrict__ pre, const float* __restrict__ Whh,
                   float* __restrict__ hout)
{
    const int tid  = threadIdx.x;
    const int wave = tid >> 6;
    const int lane = tid & 63;
    const int quad = lane >> 4;
    const int lcol = lane & 15;
    const int b    = blockIdx.x;

    // LDS layout (shorts): Hh[0]@0, Hl[0]@256, Hh[1]@512, Hl[1]@768,
    // pad@1024 (8), Z@1032 (256).  Z is +516 dwords vs Hh[0] => bank +4.
    __shared__ short lds[1288];
    for (int i = tid; i < 1288; i += 512) lds[i] = 0;

    // --- W fragments: B-operand layout, lane holds W[n=.., k=quad*8+j] ---
    short8 wh[2][8], wl[2][8];
#pragma unroll
    for (int tile = 0; tile < 2; ++tile) {
        const int n = wave * 32 + tile * 16 + lcol;
        const float* wr = Whh + (size_t)n * D_DIM + quad * 8;
#pragma unroll
        for (int kt = 0; kt < 8; ++kt) {
            float4 x0 = *(const float4*)(wr + kt * 32);
            float4 x1 = *(const float4*)(wr + kt * 32 + 4);
            float xs[8] = {x0.x, x0.y, x0.z, x0.w, x1.x, x1.y, x1.z, x1.w};
            short8 hi8, lo8;
#pragma unroll
            for (int j = 0; j < 8; ++j) {
                unsigned short h = f2bf(xs[j]);
                unsigned short l = f2bf(xs[j] - bf2f(h));
                hi8[j] = (short)h;
                lo8[j] = (short)l;
            }
            wh[tile][kt] = hi8;
            wl[tile][kt] = lo8;
        }
    }

    // per-lane A-read offsets (shorts): lane lcol==0 reads h, others read Z
    const int O_H[2] = {0, 512};
    const int aoffH0 = (lcol == 0 ? 0   : 1032) + quad * 8;
    const int aoffL0 = (lcol == 0 ? 256 : 1032) + quad * 8;
    const int aoffH1 = (lcol == 0 ? 512 : 1032) + quad * 8;
    const int aoffL1 = (lcol == 0 ? 768 : 1032) + quad * 8;

    const bool active = (lane < 16);           // quad==0; result reg r=0 row m=0
    const int n0 = wave * 32 + lcol;           // tile 0 unit
    const int n1 = n0 + 16;                    // tile 1 unit
    const size_t rowbase = (size_t)b * T_DIM * D_DIM;

    // 2-step-deep pre pipeline: pv = step t, nv = step t+1
    float pv0 = 0.f, pv1 = 0.f, nv0 = 0.f, nv1 = 0.f;
    if (active) {
        pv0 = pre[rowbase + n0];
        pv1 = pre[rowbase + n1];
        nv0 = pre[rowbase + D_DIM + n0];
        nv1 = pre[rowbase + D_DIM + n1];
    }
    lds_barrier();

    const f32x4 Z = {0.f, 0.f, 0.f, 0.f};

    for (int t = 0; t < T_DIM; ++t) {
        // prefetch step t+2's pre (2 full MFMA phases to cover HBM latency)
        float qv0 = 0.f, qv1 = 0.f;
        if (active && t + 2 < T_DIM) {
            const float* p2 = pre + rowbase + (size_t)(t + 2) * D_DIM;
            qv0 = p2[n0];
            qv1 = p2[n1];
        }

        const int aoH = (t & 1) ? aoffH1 : aoffH0;
        const int aoL = (t & 1) ? aoffL1 : aoffL0;

        short8 ah = *(const short8*)(lds + aoH);
        short8 al = *(const short8*)(lds + aoL);

        f32x4 ahh0, ahh1, alh0, alh1, ahl0, ahl1;
        {   // kt = 0 seeds the chains with the zero vector (no per-step movs)
            short8 ahn = *(const short8*)(lds + aoH + 32);
            short8 aln = *(const short8*)(lds + aoL + 32);
            ahh0 = __builtin_amdgcn_mfma_f32_16x16x32_bf16(ah, wh[0][0], Z, 0, 0, 0);
            ahh1 = __builtin_amdgcn_mfma_f32_16x16x32_bf16(ah, wh[1][0], Z, 0, 0, 0);
            alh0 = __builtin_amdgcn_mfma_f32_16x16x32_bf16(al, wh[0][0], Z, 0, 0, 0);
            alh1 = __builtin_amdgcn_mfma_f32_16x16x32_bf16(al, wh[1][0], Z, 0, 0, 0);
            ahl0 = __builtin_amdgcn_mfma_f32_16x16x32_bf16(ah, wl[0][0], Z, 0, 0, 0);
            ahl1 = __builtin_amdgcn_mfma_f32_16x16x32_bf16(ah, wl[1][0], Z, 0, 0, 0);
            ah = ahn;
            al = aln;
        }
#pragma unroll
        for (int kt = 1; kt < 8; ++kt) {
            short8 ahn, aln;
            if (kt < 7) {
                ahn = *(const short8*)(lds + aoH + (kt + 1) * 32);
                aln = *(const short8*)(lds + aoL + (kt + 1) * 32);
            } else {
                ahn = ah; aln = al;
            }
            ahh0 = __builtin_amdgcn_mfma_f32_16x16x32_bf16(ah, wh[0][kt], ahh0, 0, 0, 0);
            ahh1 = __builtin_amdgcn_mfma_f32_16x16x32_bf16(ah, wh[1][kt], ahh1, 0, 0, 0);
            alh0 = __builtin_amdgcn_mfma_f32_16x16x32_bf16(al, wh[0][kt], alh0, 0, 0, 0);
            alh1 = __builtin_amdgcn_mfma_f32_16x16x32_bf16(al, wh[1][kt], alh1, 0, 0, 0);
            ahl0 = __builtin_amdgcn_mfma_f32_16x16x32_bf16(ah, wl[0][kt], ahl0, 0, 0, 0);
            ahl1 = __builtin_amdgcn_mfma_f32_16x16x32_bf16(ah, wl[1][kt], ahl1, 0, 0, 0);
            ah = ahn;
            al = aln;
        }

        // epilogue: only lanes 0..15 hold row m=0 (reg 0)
        if (active) {
            const int wH = O_H[(t + 1) & 1];
            float x0 = ahh0[0] + alh0[0] + ahl0[0] + pv0;
            float x1 = ahh1[0] + alh1[0] + ahl1[0] + pv1;
            float h0 = fast_tanh(x0);
            float h1 = fast_tanh(x1);
            hout[rowbase + (size_t)t * D_DIM + n0] = h0;   // stays in flight
            hout[rowbase + (size_t)t * D_DIM + n1] = h1;
            unsigned short h0h = f2bf(h0);
            unsigned short h0l = f2bf(h0 - bf2f(h0h));
            unsigned short h1h = f2bf(h1);
            unsigned short h1l = f2bf(h1 - bf2f(h1h));
            lds[wH + n0]       = (short)h0h;
            lds[wH + n1]       = (short)h1h;
            lds[wH + 256 + n0] = (short)h0l;
            lds[wH + 256 + n1] = (short)h1l;
        }
        pv0 = nv0; pv1 = nv1;
        nv0 = qv0; nv1 = qv1;
        lds_barrier();
    }
}

extern "C" void kernel_launch(void* const* d_in, const int* in_sizes, int n_in,
                              void* d_out, int out_size, void* d_ws, size_t ws_size,
                              hipStream_t stream)
{
    const int*   ids    = (const int*)  d_in[0];
    const float* emb    = (const float*)d_in[1];
    const float* W_ih0  = (const float*)d_in[2];
    const float* W_hh0  = (const float*)d_in[3];
    const float* b_ih0  = (const float*)d_in[4];
    const float* b_hh0  = (const float*)d_in[5];
    const float* W_ih1  = (const float*)d_in[6];
    const float* W_hh1  = (const float*)d_in[7];
    const float* b_ih1  = (const float*)d_in[8];
    const float* b_hh1  = (const float*)d_in[9];
    const float* W_head = (const float*)d_in[10];

    float* out = (float*)d_out;
    const int M = B_DIM * T_DIM;              // 65536
    float* pre0 = out;                        // d_out doubles as scratch
    float* pre1 = out + (size_t)M * D_DIM;
    float* h1   = (float*)d_ws;               // 64 MB of ws
    float* h2   = h1;

    // pre0 = emb[ids] @ W_ih0^T + (b_ih0 + b_hh0)
    gemm_bt<<<dim3(M / 128, D_DIM / 128), dim3(256), 0, stream>>>(
        nullptr, W_ih0, pre0, b_ih0, b_hh0, ids, emb, M, D_DIM, D_DIM);
    // layer-0 recurrence (MFMA, split-bf16, 1 batch row per block)
    rnn_scan_mfma<<<dim3(B_DIM), dim3(512), 0, stream>>>(pre0, W_hh0, h1);
    // pre1 = h1 @ W_ih1^T + (b_ih1 + b_hh1)
    gemm_bt<<<dim3(M / 128, D_DIM / 128), dim3(256), 0, stream>>>(
        h1, W_ih1, pre1, b_ih1, b_hh1, nullptr, nullptr, M, D_DIM, D_DIM);
    // layer-1 recurrence
    rnn_scan_mfma<<<dim3(B_DIM), dim3(512), 0, stream>>>(pre1, W_hh1, h2);
    // logits = h2 @ W_head^T
    gemm_bt<<<dim3(M / 128, S_DIM / 128), dim3(256), 0, stream>>>(
        h2, W_head, out, nullptr, nullptr, nullptr, nullptr, M, S_DIM, D_DIM);
}

// Round 2
// 1587.203 us; speedup vs baseline: 1.0021x; 1.0021x over previous
//
#include <hip/hip_runtime.h>
#include <cstdint>
#include <cstddef>

#define D_DIM 256
#define T_DIM 512
#define B_DIM 128
#define S_DIM 512

typedef __attribute__((ext_vector_type(8))) short short8;
typedef __attribute__((ext_vector_type(4))) float f32x4;

// ---------- fp32 tiled GEMM (unchanged): C[M,N] = A @ B^T (+biases) ----------
__global__ __launch_bounds__(256, 2)
void gemm_bt(const float* __restrict__ A, const float* __restrict__ Bm,
             float* __restrict__ C,
             const float* __restrict__ bias1, const float* __restrict__ bias2,
             const int* __restrict__ ids, const float* __restrict__ emb,
             int M, int N, int K)
{
    __shared__ float As[16][128];
    __shared__ float Bs[16][128];
    const int tid = threadIdx.x;
    const int m0 = blockIdx.x * 128;
    const int n0 = blockIdx.y * 128;
    const int tx = tid & 15;
    const int ty = tid >> 4;

    float acc[8][8];
#pragma unroll
    for (int i = 0; i < 8; ++i)
#pragma unroll
        for (int j = 0; j < 8; ++j) acc[i][j] = 0.0f;

    for (int kc = 0; kc < K; kc += 16) {
#pragma unroll
        for (int p = 0; p < 2; ++p) {
            int f   = tid + p * 256;
            int row = f >> 2;
            int kq  = f & 3;
            int gm = m0 + row;
            const float* arow = ids ? (emb + (size_t)ids[gm] * K)
                                    : (A + (size_t)gm * K);
            float4 v = *(const float4*)(arow + kc + kq * 4);
            As[kq * 4 + 0][row] = v.x;
            As[kq * 4 + 1][row] = v.y;
            As[kq * 4 + 2][row] = v.z;
            As[kq * 4 + 3][row] = v.w;
            const float* brow = Bm + (size_t)(n0 + row) * K;
            float4 w = *(const float4*)(brow + kc + kq * 4);
            Bs[kq * 4 + 0][row] = w.x;
            Bs[kq * 4 + 1][row] = w.y;
            Bs[kq * 4 + 2][row] = w.z;
            Bs[kq * 4 + 3][row] = w.w;
        }
        __syncthreads();
#pragma unroll
        for (int k = 0; k < 16; ++k) {
            float a[8], b[8];
            *(float4*)&a[0] = *(const float4*)&As[k][ty * 8];
            *(float4*)&a[4] = *(const float4*)&As[k][ty * 8 + 4];
            *(float4*)&b[0] = *(const float4*)&Bs[k][tx * 8];
            *(float4*)&b[4] = *(const float4*)&Bs[k][tx * 8 + 4];
#pragma unroll
            for (int i = 0; i < 8; ++i)
#pragma unroll
                for (int j = 0; j < 8; ++j) acc[i][j] += a[i] * b[j];
        }
        __syncthreads();
    }

    float bv[8];
#pragma unroll
    for (int j = 0; j < 8; ++j) {
        int gn = n0 + tx * 8 + j;
        float v = 0.0f;
        if (bias1) v += bias1[gn];
        if (bias2) v += bias2[gn];
        bv[j] = v;
    }
#pragma unroll
    for (int i = 0; i < 8; ++i) {
        int gm = m0 + ty * 8 + i;
        float* crow = C + (size_t)gm * N + n0 + tx * 8;
        float4 v0 = make_float4(acc[i][0] + bv[0], acc[i][1] + bv[1],
                                acc[i][2] + bv[2], acc[i][3] + bv[3]);
        float4 v1 = make_float4(acc[i][4] + bv[4], acc[i][5] + bv[5],
                                acc[i][6] + bv[6], acc[i][7] + bv[7]);
        *(float4*)(crow)     = v0;
        *(float4*)(crow + 4) = v1;
    }
}

// ---------- helpers ----------
__device__ inline unsigned short f2bf(float x) {
    unsigned u = __builtin_bit_cast(unsigned, x);
    unsigned r = (u + 0x7fffu + ((u >> 16) & 1u)) >> 16;
    return (unsigned short)r;
}
__device__ inline float bf2f(unsigned short b) {
    unsigned u = ((unsigned)b) << 16;
    return __builtin_bit_cast(float, u);
}
__device__ inline float fast_tanh(float x) {
    float ax = __builtin_fabsf(x);
    float e  = __expf(-2.0f * ax);
    float r  = (1.0f - e) * __builtin_amdgcn_rcpf(1.0f + e);
    return __builtin_copysignf(r, x);
}

// LDS-only barrier (R1: neutral vs __syncthreads, kept because harmless and
// it documents the intent: only the LDS h-write -> h-read needs ordering).
__device__ inline void lds_barrier() {
    asm volatile("s_waitcnt lgkmcnt(0)" ::: "memory");
    __builtin_amdgcn_s_barrier();
    __builtin_amdgcn_sched_barrier(0);
}

// ---------- MFMA Elman scan, one batch row per block ----------
// R1 theory: the 16 ds_read_b128/wave/step of the A operand moved 1 KiB each
// through the LDS return path (~10 cyc apiece; 8 waves -> ~1300 cyc/step of
// LDS pipe) even though 60/64 lanes read the shared zero region.  Fix: A
// fragments live in PERSISTENT zero-initialized registers (aH[8], aL[8]);
// only lanes lcol==0 (rows m=0 holders: lanes 0,16,32,48) do exec-masked
// ds_reads each step.  Inactive lanes never write -> stay zero across all
// 512 steps.  Each read now returns 4 lanes x 16B, conflict-free.
__global__ __launch_bounds__(512) __attribute__((amdgpu_waves_per_eu(2, 2)))
void rnn_scan_mfma(const float* __restrict__ pre, const float* __restrict__ Whh,
                   float* __restrict__ hout)
{
    const int tid  = threadIdx.x;
    const int wave = tid >> 6;
    const int lane = tid & 63;
    const int quad = lane >> 4;
    const int lcol = lane & 15;
    const int b    = blockIdx.x;

    // LDS layout (shorts): Hh[0]@0, Hl[0]@256, Hh[1]@512, Hl[1]@768.
    __shared__ short lds[1024];
    for (int i = tid; i < 1024; i += 512) lds[i] = 0;

    // --- W fragments: B-operand layout, lane holds W[n=.., k=quad*8+j] ---
    short8 wh[2][8], wl[2][8];
#pragma unroll
    for (int tile = 0; tile < 2; ++tile) {
        const int n = wave * 32 + tile * 16 + lcol;
        const float* wr = Whh + (size_t)n * D_DIM + quad * 8;
#pragma unroll
        for (int kt = 0; kt < 8; ++kt) {
            float4 x0 = *(const float4*)(wr + kt * 32);
            float4 x1 = *(const float4*)(wr + kt * 32 + 4);
            float xs[8] = {x0.x, x0.y, x0.z, x0.w, x1.x, x1.y, x1.z, x1.w};
            short8 hi8, lo8;
#pragma unroll
            for (int j = 0; j < 8; ++j) {
                unsigned short h = f2bf(xs[j]);
                unsigned short l = f2bf(xs[j] - bf2f(h));
                hi8[j] = (short)h;
                lo8[j] = (short)l;
            }
            wh[tile][kt] = hi8;
            wl[tile][kt] = lo8;
        }
    }

    const bool active = (lane < 16);           // quad==0; result reg r=0 row m=0
    const int n0 = wave * 32 + lcol;           // tile 0 unit
    const int n1 = n0 + 16;                    // tile 1 unit
    const size_t rowbase = (size_t)b * T_DIM * D_DIM;

    // Persistent A-fragment registers; only lanes lcol==0 ever overwrite.
    const short8 ZS = {0, 0, 0, 0, 0, 0, 0, 0};
    short8 aH[8], aL[8];
#pragma unroll
    for (int kt = 0; kt < 8; ++kt) { aH[kt] = ZS; aL[kt] = ZS; }

    // per-(active)lane read base within a buffer: quad's k-chunk
    const int aq = quad * 8;

    // 2-step-deep pre pipeline: pv = step t, nv = step t+1
    float pv0 = 0.f, pv1 = 0.f, nv0 = 0.f, nv1 = 0.f;
    if (active) {
        pv0 = pre[rowbase + n0];
        pv1 = pre[rowbase + n1];
        nv0 = pre[rowbase + D_DIM + n0];
        nv1 = pre[rowbase + D_DIM + n1];
    }
    lds_barrier();

    const f32x4 Z = {0.f, 0.f, 0.f, 0.f};

    for (int t = 0; t < T_DIM; ++t) {
        // prefetch step t+2's pre (2 full MFMA phases to cover HBM latency)
        float qv0 = 0.f, qv1 = 0.f;
        if (active && t + 2 < T_DIM) {
            const float* p2 = pre + rowbase + (size_t)(t + 2) * D_DIM;
            qv0 = p2[n0];
            qv1 = p2[n1];
        }

        // exec-masked A-fragment loads: 4 lanes x 16B per read, banks 0..15
        // (kt even) / 16..31 (kt odd) per quad -> conflict-free.
        const int bh = (t & 1) ? 512 : 0;
        if (lcol == 0) {
            const short* ph = lds + bh + aq;
            const short* pl = ph + 256;
#pragma unroll
            for (int kt = 0; kt < 8; ++kt) {
                aH[kt] = *(const short8*)(ph + kt * 32);
                aL[kt] = *(const short8*)(pl + kt * 32);
            }
        }

        f32x4 ahh0, ahh1, alh0, alh1, ahl0, ahl1;
        // kt = 0 seeds the chains with the zero vector (no per-step acc movs)
        ahh0 = __builtin_amdgcn_mfma_f32_16x16x32_bf16(aH[0], wh[0][0], Z, 0, 0, 0);
        ahh1 = __builtin_amdgcn_mfma_f32_16x16x32_bf16(aH[0], wh[1][0], Z, 0, 0, 0);
        alh0 = __builtin_amdgcn_mfma_f32_16x16x32_bf16(aL[0], wh[0][0], Z, 0, 0, 0);
        alh1 = __builtin_amdgcn_mfma_f32_16x16x32_bf16(aL[0], wh[1][0], Z, 0, 0, 0);
        ahl0 = __builtin_amdgcn_mfma_f32_16x16x32_bf16(aH[0], wl[0][0], Z, 0, 0, 0);
        ahl1 = __builtin_amdgcn_mfma_f32_16x16x32_bf16(aH[0], wl[1][0], Z, 0, 0, 0);
#pragma unroll
        for (int kt = 1; kt < 8; ++kt) {
            ahh0 = __builtin_amdgcn_mfma_f32_16x16x32_bf16(aH[kt], wh[0][kt], ahh0, 0, 0, 0);
            ahh1 = __builtin_amdgcn_mfma_f32_16x16x32_bf16(aH[kt], wh[1][kt], ahh1, 0, 0, 0);
            alh0 = __builtin_amdgcn_mfma_f32_16x16x32_bf16(aL[kt], wh[0][kt], alh0, 0, 0, 0);
            alh1 = __builtin_amdgcn_mfma_f32_16x16x32_bf16(aL[kt], wh[1][kt], alh1, 0, 0, 0);
            ahl0 = __builtin_amdgcn_mfma_f32_16x16x32_bf16(aH[kt], wl[0][kt], ahl0, 0, 0, 0);
            ahl1 = __builtin_amdgcn_mfma_f32_16x16x32_bf16(aH[kt], wl[1][kt], ahl1, 0, 0, 0);
        }

        // epilogue: only lanes 0..15 hold row m=0 (reg 0)
        if (active) {
            const int wH = (t & 1) ? 0 : 512;   // write the other buffer
            float x0 = ahh0[0] + alh0[0] + ahl0[0] + pv0;
            float x1 = ahh1[0] + alh1[0] + ahl1[0] + pv1;
            float h0 = fast_tanh(x0);
            float h1 = fast_tanh(x1);
            hout[rowbase + (size_t)t * D_DIM + n0] = h0;   // stays in flight
            hout[rowbase + (size_t)t * D_DIM + n1] = h1;
            unsigned short h0h = f2bf(h0);
            unsigned short h0l = f2bf(h0 - bf2f(h0h));
            unsigned short h1h = f2bf(h1);
            unsigned short h1l = f2bf(h1 - bf2f(h1h));
            lds[wH + n0]       = (short)h0h;
            lds[wH + n1]       = (short)h1h;
            lds[wH + 256 + n0] = (short)h0l;
            lds[wH + 256 + n1] = (short)h1l;
        }
        pv0 = nv0; pv1 = nv1;
        nv0 = qv0; nv1 = qv1;
        lds_barrier();
    }
}

extern "C" void kernel_launch(void* const* d_in, const int* in_sizes, int n_in,
                              void* d_out, int out_size, void* d_ws, size_t ws_size,
                              hipStream_t stream)
{
    const int*   ids    = (const int*)  d_in[0];
    const float* emb    = (const float*)d_in[1];
    const float* W_ih0  = (const float*)d_in[2];
    const float* W_hh0  = (const float*)d_in[3];
    const float* b_ih0  = (const float*)d_in[4];
    const float* b_hh0  = (const float*)d_in[5];
    const float* W_ih1  = (const float*)d_in[6];
    const float* W_hh1  = (const float*)d_in[7];
    const float* b_ih1  = (const float*)d_in[8];
    const float* b_hh1  = (const float*)d_in[9];
    const float* W_head = (const float*)d_in[10];

    float* out = (float*)d_out;
    const int M = B_DIM * T_DIM;              // 65536
    float* pre0 = out;                        // d_out doubles as scratch
    float* pre1 = out + (size_t)M * D_DIM;
    float* h1   = (float*)d_ws;               // 64 MB of ws
    float* h2   = h1;

    // pre0 = emb[ids] @ W_ih0^T + (b_ih0 + b_hh0)
    gemm_bt<<<dim3(M / 128, D_DIM / 128), dim3(256), 0, stream>>>(
        nullptr, W_ih0, pre0, b_ih0, b_hh0, ids, emb, M, D_DIM, D_DIM);
    // layer-0 recurrence (MFMA, split-bf16, 1 batch row per block)
    rnn_scan_mfma<<<dim3(B_DIM), dim3(512), 0, stream>>>(pre0, W_hh0, h1);
    // pre1 = h1 @ W_ih1^T + (b_ih1 + b_hh1)
    gemm_bt<<<dim3(M / 128, D_DIM / 128), dim3(256), 0, stream>>>(
        h1, W_ih1, pre1, b_ih1, b_hh1, nullptr, nullptr, M, D_DIM, D_DIM);
    // layer-1 recurrence
    rnn_scan_mfma<<<dim3(B_DIM), dim3(512), 0, stream>>>(pre1, W_hh1, h2);
    // logits = h2 @ W_head^T
    gemm_bt<<<dim3(M / 128, S_DIM / 128), dim3(256), 0, stream>>>(
        h2, W_head, out, nullptr, nullptr, nullptr, nullptr, M, S_DIM, D_DIM);
}

// Round 3
// 1378.619 us; speedup vs baseline: 1.1537x; 1.1513x over previous
//
#include <hip/hip_runtime.h>
#include <cstdint>
#include <cstddef>

#define D_DIM 256
#define T_DIM 512
#define B_DIM 128
#define S_DIM 512

typedef __attribute__((ext_vector_type(8))) short short8;
typedef __attribute__((ext_vector_type(4))) float f32x4;

// ---------- fp32 tiled GEMM (unchanged): C[M,N] = A @ B^T (+biases) ----------
__global__ __launch_bounds__(256, 2)
void gemm_bt(const float* __restrict__ A, const float* __restrict__ Bm,
             float* __restrict__ C,
             const float* __restrict__ bias1, const float* __restrict__ bias2,
             const int* __restrict__ ids, const float* __restrict__ emb,
             int M, int N, int K)
{
    __shared__ float As[16][128];
    __shared__ float Bs[16][128];
    const int tid = threadIdx.x;
    const int m0 = blockIdx.x * 128;
    const int n0 = blockIdx.y * 128;
    const int tx = tid & 15;
    const int ty = tid >> 4;

    float acc[8][8];
#pragma unroll
    for (int i = 0; i < 8; ++i)
#pragma unroll
        for (int j = 0; j < 8; ++j) acc[i][j] = 0.0f;

    for (int kc = 0; kc < K; kc += 16) {
#pragma unroll
        for (int p = 0; p < 2; ++p) {
            int f   = tid + p * 256;
            int row = f >> 2;
            int kq  = f & 3;
            int gm = m0 + row;
            const float* arow = ids ? (emb + (size_t)ids[gm] * K)
                                    : (A + (size_t)gm * K);
            float4 v = *(const float4*)(arow + kc + kq * 4);
            As[kq * 4 + 0][row] = v.x;
            As[kq * 4 + 1][row] = v.y;
            As[kq * 4 + 2][row] = v.z;
            As[kq * 4 + 3][row] = v.w;
            const float* brow = Bm + (size_t)(n0 + row) * K;
            float4 w = *(const float4*)(brow + kc + kq * 4);
            Bs[kq * 4 + 0][row] = w.x;
            Bs[kq * 4 + 1][row] = w.y;
            Bs[kq * 4 + 2][row] = w.z;
            Bs[kq * 4 + 3][row] = w.w;
        }
        __syncthreads();
#pragma unroll
        for (int k = 0; k < 16; ++k) {
            float a[8], b[8];
            *(float4*)&a[0] = *(const float4*)&As[k][ty * 8];
            *(float4*)&a[4] = *(const float4*)&As[k][ty * 8 + 4];
            *(float4*)&b[0] = *(const float4*)&Bs[k][tx * 8];
            *(float4*)&b[4] = *(const float4*)&Bs[k][tx * 8 + 4];
#pragma unroll
            for (int i = 0; i < 8; ++i)
#pragma unroll
                for (int j = 0; j < 8; ++j) acc[i][j] += a[i] * b[j];
        }
        __syncthreads();
    }

    float bv[8];
#pragma unroll
    for (int j = 0; j < 8; ++j) {
        int gn = n0 + tx * 8 + j;
        float v = 0.0f;
        if (bias1) v += bias1[gn];
        if (bias2) v += bias2[gn];
        bv[j] = v;
    }
#pragma unroll
    for (int i = 0; i < 8; ++i) {
        int gm = m0 + ty * 8 + i;
        float* crow = C + (size_t)gm * N + n0 + tx * 8;
        float4 v0 = make_float4(acc[i][0] + bv[0], acc[i][1] + bv[1],
                                acc[i][2] + bv[2], acc[i][3] + bv[3]);
        float4 v1 = make_float4(acc[i][4] + bv[4], acc[i][5] + bv[5],
                                acc[i][6] + bv[6], acc[i][7] + bv[7]);
        *(float4*)(crow)     = v0;
        *(float4*)(crow + 4) = v1;
    }
}

// ---------- helpers ----------
__device__ inline unsigned short f2bf(float x) {
    unsigned u = __builtin_bit_cast(unsigned, x);
    unsigned r = (u + 0x7fffu + ((u >> 16) & 1u)) >> 16;
    return (unsigned short)r;
}
__device__ inline float bf2f(unsigned short b) {
    unsigned u = ((unsigned)b) << 16;
    return __builtin_bit_cast(float, u);
}
__device__ inline float fast_tanh(float x) {
    float ax = __builtin_fabsf(x);
    float e  = __expf(-2.0f * ax);
    float r  = (1.0f - e) * __builtin_amdgcn_rcpf(1.0f + e);
    return __builtin_copysignf(r, x);
}

// LDS-only barrier (R1: neutral vs __syncthreads; kept, documents intent).
__device__ inline void lds_barrier() {
    asm volatile("s_waitcnt lgkmcnt(0)" ::: "memory");
    __builtin_amdgcn_s_barrier();
    __builtin_amdgcn_sched_barrier(0);
}

// ---------- MFMA Elman scan, one batch row per block ----------
// R2 accounting: 16x16x32 bf16 MFMA throughput is ~4.85 cyc/CU (m06 ceiling,
// chip-level).  48 MFMA/wave/step x 8 waves = 384/CU/step -> 1862-cycle floor
// of the measured 2570-cycle step: the kernel is MFMA-THROUGHPUT-bound at CU
// level (explains R0-R2 neutrality of barrier/LDS changes).
// Fix: A-ROW PACKING.  hh and lh share B=wh, so pack h_hi into A-row 0 and
// h_lo into A-row 1 of ONE fragment: a single MFMA yields hh (C-row 0 =
// reg[0]) and lh (C-row 1 = reg[1]).  The hl product (B=wl) reuses the same
// packed A; its C-row 1 (ll term) is never read.  48 -> 32 MFMA/wave/step,
// identical per-product accumulation; final 3-term fp32 sum reordered only.
__global__ __launch_bounds__(512) __attribute__((amdgpu_waves_per_eu(2, 2)))
void rnn_scan_mfma(const float* __restrict__ pre, const float* __restrict__ Whh,
                   float* __restrict__ hout)
{
    const int tid  = threadIdx.x;
    const int wave = tid >> 6;
    const int lane = tid & 63;
    const int quad = lane >> 4;
    const int lcol = lane & 15;
    const int b    = blockIdx.x;

    // LDS layout (shorts): Hh[0]@0, Hl[0]@256, Hh[1]@512, Hl[1]@768.
    __shared__ short lds[1024];
    for (int i = tid; i < 1024; i += 512) lds[i] = 0;

    // --- W fragments: B-operand layout, lane holds W[n=.., k=quad*8+j] ---
    short8 wh[2][8], wl[2][8];
#pragma unroll
    for (int tile = 0; tile < 2; ++tile) {
        const int n = wave * 32 + tile * 16 + lcol;
        const float* wr = Whh + (size_t)n * D_DIM + quad * 8;
#pragma unroll
        for (int kt = 0; kt < 8; ++kt) {
            float4 x0 = *(const float4*)(wr + kt * 32);
            float4 x1 = *(const float4*)(wr + kt * 32 + 4);
            float xs[8] = {x0.x, x0.y, x0.z, x0.w, x1.x, x1.y, x1.z, x1.w};
            short8 hi8, lo8;
#pragma unroll
            for (int j = 0; j < 8; ++j) {
                unsigned short h = f2bf(xs[j]);
                unsigned short l = f2bf(xs[j] - bf2f(h));
                hi8[j] = (short)h;
                lo8[j] = (short)l;
            }
            wh[tile][kt] = hi8;
            wl[tile][kt] = lo8;
        }
    }

    const bool active = (lane < 16);           // quad==0 holds C rows 0..3
    const int n0 = wave * 32 + lcol;           // tile 0 unit
    const int n1 = n0 + 16;                    // tile 1 unit
    const size_t rowbase = (size_t)b * T_DIM * D_DIM;

    // Persistent packed A fragment: row 0 (lanes lcol==0) = h_hi chunk,
    // row 1 (lanes lcol==1) = h_lo chunk, rows 2..15 permanently zero.
    const short8 ZS = {0, 0, 0, 0, 0, 0, 0, 0};
    short8 aP[8];
#pragma unroll
    for (int kt = 0; kt < 8; ++kt) aP[kt] = ZS;

    const int aq = quad * 8;                   // k-chunk within buffer

    // 2-step-deep pre pipeline: pv = step t, nv = step t+1
    float pv0 = 0.f, pv1 = 0.f, nv0 = 0.f, nv1 = 0.f;
    if (active) {
        pv0 = pre[rowbase + n0];
        pv1 = pre[rowbase + n1];
        nv0 = pre[rowbase + D_DIM + n0];
        nv1 = pre[rowbase + D_DIM + n1];
    }
    lds_barrier();

    const f32x4 Z = {0.f, 0.f, 0.f, 0.f};

    for (int t = 0; t < T_DIM; ++t) {
        // prefetch step t+2's pre
        float qv0 = 0.f, qv1 = 0.f;
        if (active && t + 2 < T_DIM) {
            const float* p2 = pre + rowbase + (size_t)(t + 2) * D_DIM;
            qv0 = p2[n0];
            qv1 = p2[n1];
        }

        // exec-masked A loads: lanes lcol==0 read h_hi, lcol==1 read h_lo
        // (Hl is +256 shorts = +512 B: same banks as Hh -> 2-way, free).
        const int bh = (t & 1) ? 512 : 0;
        if (lcol < 2) {
            const short* pa = lds + bh + lcol * 256 + aq;
#pragma unroll
            for (int kt = 0; kt < 8; ++kt)
                aP[kt] = *(const short8*)(pa + kt * 32);
        }

        // 4 chains: acc1_* (B=wh: row0=hh, row1=lh), acc2_* (B=wl: row0=hl)
        f32x4 a1t0, a1t1, a2t0, a2t1;
        a1t0 = __builtin_amdgcn_mfma_f32_16x16x32_bf16(aP[0], wh[0][0], Z, 0, 0, 0);
        a1t1 = __builtin_amdgcn_mfma_f32_16x16x32_bf16(aP[0], wh[1][0], Z, 0, 0, 0);
        a2t0 = __builtin_amdgcn_mfma_f32_16x16x32_bf16(aP[0], wl[0][0], Z, 0, 0, 0);
        a2t1 = __builtin_amdgcn_mfma_f32_16x16x32_bf16(aP[0], wl[1][0], Z, 0, 0, 0);
#pragma unroll
        for (int kt = 1; kt < 8; ++kt) {
            a1t0 = __builtin_amdgcn_mfma_f32_16x16x32_bf16(aP[kt], wh[0][kt], a1t0, 0, 0, 0);
            a1t1 = __builtin_amdgcn_mfma_f32_16x16x32_bf16(aP[kt], wh[1][kt], a1t1, 0, 0, 0);
            a2t0 = __builtin_amdgcn_mfma_f32_16x16x32_bf16(aP[kt], wl[0][kt], a2t0, 0, 0, 0);
            a2t1 = __builtin_amdgcn_mfma_f32_16x16x32_bf16(aP[kt], wl[1][kt], a2t1, 0, 0, 0);
        }

        // epilogue: lanes 0..15 hold C rows 0 (reg 0: hh/hl) and 1 (reg 1: lh)
        if (active) {
            const int wH = (t & 1) ? 0 : 512;   // write the other buffer
            float x0 = a1t0[0] + a1t0[1] + a2t0[0] + pv0;
            float x1 = a1t1[0] + a1t1[1] + a2t1[0] + pv1;
            float h0 = fast_tanh(x0);
            float h1 = fast_tanh(x1);
            hout[rowbase + (size_t)t * D_DIM + n0] = h0;   // stays in flight
            hout[rowbase + (size_t)t * D_DIM + n1] = h1;
            unsigned short h0h = f2bf(h0);
            unsigned short h0l = f2bf(h0 - bf2f(h0h));
            unsigned short h1h = f2bf(h1);
            unsigned short h1l = f2bf(h1 - bf2f(h1h));
            lds[wH + n0]       = (short)h0h;
            lds[wH + n1]       = (short)h1h;
            lds[wH + 256 + n0] = (short)h0l;
            lds[wH + 256 + n1] = (short)h1l;
        }
        pv0 = nv0; pv1 = nv1;
        nv0 = qv0; nv1 = qv1;
        lds_barrier();
    }
}

extern "C" void kernel_launch(void* const* d_in, const int* in_sizes, int n_in,
                              void* d_out, int out_size, void* d_ws, size_t ws_size,
                              hipStream_t stream)
{
    const int*   ids    = (const int*)  d_in[0];
    const float* emb    = (const float*)d_in[1];
    const float* W_ih0  = (const float*)d_in[2];
    const float* W_hh0  = (const float*)d_in[3];
    const float* b_ih0  = (const float*)d_in[4];
    const float* b_hh0  = (const float*)d_in[5];
    const float* W_ih1  = (const float*)d_in[6];
    const float* W_hh1  = (const float*)d_in[7];
    const float* b_ih1  = (const float*)d_in[8];
    const float* b_hh1  = (const float*)d_in[9];
    const float* W_head = (const float*)d_in[10];

    float* out = (float*)d_out;
    const int M = B_DIM * T_DIM;              // 65536
    float* pre0 = out;                        // d_out doubles as scratch
    float* pre1 = out + (size_t)M * D_DIM;
    float* h1   = (float*)d_ws;               // 64 MB of ws
    float* h2   = h1;

    // pre0 = emb[ids] @ W_ih0^T + (b_ih0 + b_hh0)
    gemm_bt<<<dim3(M / 128, D_DIM / 128), dim3(256), 0, stream>>>(
        nullptr, W_ih0, pre0, b_ih0, b_hh0, ids, emb, M, D_DIM, D_DIM);
    // layer-0 recurrence (MFMA, A-row-packed split-bf16, 1 batch row/block)
    rnn_scan_mfma<<<dim3(B_DIM), dim3(512), 0, stream>>>(pre0, W_hh0, h1);
    // pre1 = h1 @ W_ih1^T + (b_ih1 + b_hh1)
    gemm_bt<<<dim3(M / 128, D_DIM / 128), dim3(256), 0, stream>>>(
        h1, W_ih1, pre1, b_ih1, b_hh1, nullptr, nullptr, M, D_DIM, D_DIM);
    // layer-1 recurrence
    rnn_scan_mfma<<<dim3(B_DIM), dim3(512), 0, stream>>>(pre1, W_hh1, h2);
    // logits = h2 @ W_head^T
    gemm_bt<<<dim3(M / 128, S_DIM / 128), dim3(256), 0, stream>>>(
        h2, W_head, out, nullptr, nullptr, nullptr, nullptr, M, S_DIM, D_DIM);
}

// Round 4
// 1127.651 us; speedup vs baseline: 1.4105x; 1.2226x over previous
//
#include <hip/hip_runtime.h>
#include <cstdint>
#include <cstddef>

#define D_DIM 256
#define T_DIM 512
#define B_DIM 128
#define S_DIM 512

typedef __attribute__((ext_vector_type(8))) short short8;
typedef __attribute__((ext_vector_type(4))) float f32x4;

// ---------- helpers ----------
__device__ inline unsigned short f2bf(float x) {
    unsigned u = __builtin_bit_cast(unsigned, x);
    unsigned r = (u + 0x7fffu + ((u >> 16) & 1u)) >> 16;
    return (unsigned short)r;
}
__device__ inline float bf2f(unsigned short b) {
    unsigned u = ((unsigned)b) << 16;
    return __builtin_bit_cast(float, u);
}
__device__ inline float fast_tanh(float x) {
    float ax = __builtin_fabsf(x);
    float e  = __expf(-2.0f * ax);
    float r  = (1.0f - e) * __builtin_amdgcn_rcpf(1.0f + e);
    return __builtin_copysignf(r, x);
}

// Truncation split: x = bf2f(hi) + (lo-term), residual exact (same exponent
// subtraction), lo truncated -> total err <= 2^-16 |x|.  Pair-packed, ~3
// VALU/elem.  Order: low 16 bits of .x = element 0 (little-endian short8).
__device__ inline void split4(float4 v, uint2& hi, uint2& lo) {
    unsigned u0 = __builtin_bit_cast(unsigned, v.x);
    unsigned u1 = __builtin_bit_cast(unsigned, v.y);
    unsigned u2 = __builtin_bit_cast(unsigned, v.z);
    unsigned u3 = __builtin_bit_cast(unsigned, v.w);
    hi.x = (u0 >> 16) | (u1 & 0xFFFF0000u);
    hi.y = (u2 >> 16) | (u3 & 0xFFFF0000u);
    float r0 = v.x - __builtin_bit_cast(float, u0 & 0xFFFF0000u);
    float r1 = v.y - __builtin_bit_cast(float, u1 & 0xFFFF0000u);
    float r2 = v.z - __builtin_bit_cast(float, u2 & 0xFFFF0000u);
    float r3 = v.w - __builtin_bit_cast(float, u3 & 0xFFFF0000u);
    lo.x = (__builtin_bit_cast(unsigned, r0) >> 16)
         | (__builtin_bit_cast(unsigned, r1) & 0xFFFF0000u);
    lo.y = (__builtin_bit_cast(unsigned, r2) >> 16)
         | (__builtin_bit_cast(unsigned, r3) & 0xFFFF0000u);
}

// ---------- split-bf16 MFMA GEMM: C[M,N] = A @ B^T (+biases) ----------
// R3: the fp32 VALU GEMMs (~485 us total) move to MFMA.  4-product split
// (hh+lh+hl+ll) -> ~fp32 accuracy.  128x128 tile, BK=64, 4 waves each 64x64
// (mt=nt=4).  LDS tiles bf16 hi/lo with XOR swizzle ((row&7)<<4) to kill the
// stride-128B 16-way bank conflict on ds_read_b128 (T2 pattern).  A-operand
// prefetched one BK-iter ahead; B issued pre-barrier (L2-resident).
__global__ __launch_bounds__(256, 2)
void gemm_bt_mfma(const float* __restrict__ A, const float* __restrict__ Bm,
                  float* __restrict__ C,
                  const float* __restrict__ bias1, const float* __restrict__ bias2,
                  const int* __restrict__ ids, const float* __restrict__ emb,
                  int M, int N, int K)
{
    // LDS planes (bf16, [128 rows][64 k], row stride 128 B, swizzled):
    // Ahi @0, Alo @16K, Bhi @32K, Blo @48K  -> 64 KB total.
    __shared__ char smem[65536];

    const int tid  = threadIdx.x;
    const int lane = tid & 63;
    const int quad = lane >> 4;
    const int lcol = lane & 15;
    const int wv   = tid >> 6;
    const int wm   = (wv & 1) * 64;    // wave m-offset in tile
    const int wn   = (wv >> 1) * 64;   // wave n-offset in tile
    const int m0   = blockIdx.x * 128;
    const int n0   = blockIdx.y * 128;

    // staging map: thread covers rows rm+16i (i=0..7), float4-col kq.
    const int rm = tid >> 4;           // 0..15
    const int kq = tid & 15;           // 0..15  (float4 within BK=64)

    const float* arowp[8];
    const float* browp[8];
#pragma unroll
    for (int i = 0; i < 8; ++i) {
        int gm = m0 + rm + i * 16;
        arowp[i] = ids ? (emb + (size_t)ids[gm] * K) : (A + (size_t)gm * K);
        browp[i] = Bm + (size_t)(n0 + rm + i * 16) * K;
    }
    // per-thread swizzled LDS write offset (same for all planes)
    int woff[8];
#pragma unroll
    for (int i = 0; i < 8; ++i) {
        int m = rm + i * 16;
        woff[i] = (m * 128 + kq * 8) ^ ((m & 7) << 4);
    }

    f32x4 acc[4][4];
#pragma unroll
    for (int mt = 0; mt < 4; ++mt)
#pragma unroll
        for (int nt = 0; nt < 4; ++nt) acc[mt][nt] = (f32x4){0.f, 0.f, 0.f, 0.f};

    // prologue: prefetch A for iter 0
    float4 pa[8];
#pragma unroll
    for (int i = 0; i < 8; ++i)
        pa[i] = *(const float4*)(arowp[i] + kq * 4);

    for (int it = 0; it < 4; ++it) {
        const int kc = it * 64;
        // issue B loads early (before barrier; LDS untouched by them)
        float4 pb[8];
#pragma unroll
        for (int i = 0; i < 8; ++i)
            pb[i] = *(const float4*)(browp[i] + kc + kq * 4);

        if (it) __syncthreads();       // prior tile's reads complete

#pragma unroll
        for (int i = 0; i < 8; ++i) {
            uint2 hi, lo;
            split4(pa[i], hi, lo);
            *(uint2*)(smem + 0     + woff[i]) = hi;
            *(uint2*)(smem + 16384 + woff[i]) = lo;
        }
#pragma unroll
        for (int i = 0; i < 8; ++i) {
            uint2 hi, lo;
            split4(pb[i], hi, lo);
            *(uint2*)(smem + 32768 + woff[i]) = hi;
            *(uint2*)(smem + 49152 + woff[i]) = lo;
        }
        __syncthreads();

        if (it < 3) {                  // prefetch next A tile under compute
#pragma unroll
            for (int i = 0; i < 8; ++i)
                pa[i] = *(const float4*)(arowp[i] + kc + 64 + kq * 4);
        }

#pragma unroll
        for (int ks = 0; ks < 2; ++ks) {
            short8 aHi[4], aLo[4], bHi[4], bLo[4];
#pragma unroll
            for (int mt = 0; mt < 4; ++mt) {
                int m = wm + mt * 16 + lcol;
                int off = (m * 128 + ks * 64 + quad * 16) ^ ((m & 7) << 4);
                aHi[mt] = *(const short8*)(smem + off);
                aLo[mt] = *(const short8*)(smem + 16384 + off);
            }
#pragma unroll
            for (int nt = 0; nt < 4; ++nt) {
                int n = wn + nt * 16 + lcol;
                int off = (n * 128 + ks * 64 + quad * 16) ^ ((n & 7) << 4);
                bHi[nt] = *(const short8*)(smem + 32768 + off);
                bLo[nt] = *(const short8*)(smem + 49152 + off);
            }
#pragma unroll
            for (int mt = 0; mt < 4; ++mt)
#pragma unroll
                for (int nt = 0; nt < 4; ++nt) {
                    acc[mt][nt] = __builtin_amdgcn_mfma_f32_16x16x32_bf16(aHi[mt], bHi[nt], acc[mt][nt], 0, 0, 0);
                    acc[mt][nt] = __builtin_amdgcn_mfma_f32_16x16x32_bf16(aLo[mt], bHi[nt], acc[mt][nt], 0, 0, 0);
                    acc[mt][nt] = __builtin_amdgcn_mfma_f32_16x16x32_bf16(aHi[mt], bLo[nt], acc[mt][nt], 0, 0, 0);
                    acc[mt][nt] = __builtin_amdgcn_mfma_f32_16x16x32_bf16(aLo[mt], bLo[nt], acc[mt][nt], 0, 0, 0);
                }
        }
    }

    // epilogue: D row = quad*4 + reg, col = lcol (per 16x16 fragment)
    float bv[4];
#pragma unroll
    for (int nt = 0; nt < 4; ++nt) {
        int gn = n0 + wn + nt * 16 + lcol;
        float v = 0.f;
        if (bias1) v += bias1[gn];
        if (bias2) v += bias2[gn];
        bv[nt] = v;
    }
#pragma unroll
    for (int mt = 0; mt < 4; ++mt) {
        int gmb = m0 + wm + mt * 16 + quad * 4;
#pragma unroll
        for (int r = 0; r < 4; ++r) {
            float* crow = C + (size_t)(gmb + r) * N + n0 + wn;
#pragma unroll
            for (int nt = 0; nt < 4; ++nt)
                crow[nt * 16 + lcol] = acc[mt][nt][r] + bv[nt];
        }
    }
}

// LDS-only barrier (R1: neutral vs __syncthreads; kept, documents intent).
__device__ inline void lds_barrier() {
    asm volatile("s_waitcnt lgkmcnt(0)" ::: "memory");
    __builtin_amdgcn_s_barrier();
    __builtin_amdgcn_sched_barrier(0);
}

// ---------- MFMA Elman scan (R3 version, unchanged): A-row-packed ----------
// hh and lh share B=wh: h_hi in A-row 0, h_lo in A-row 1 -> one MFMA gives
// hh (C reg[0]) and lh (C reg[1]).  hl via B=wl on same packed A.  32
// MFMA/wave/step; measured 447 us (step 2095 cyc vs 1241-cyc MFMA floor).
__global__ __launch_bounds__(512) __attribute__((amdgpu_waves_per_eu(2, 2)))
void rnn_scan_mfma(const float* __restrict__ pre, const float* __restrict__ Whh,
                   float* __restrict__ hout)
{
    const int tid  = threadIdx.x;
    const int wave = tid >> 6;
    const int lane = tid & 63;
    const int quad = lane >> 4;
    const int lcol = lane & 15;
    const int b    = blockIdx.x;

    // LDS layout (shorts): Hh[0]@0, Hl[0]@256, Hh[1]@512, Hl[1]@768.
    __shared__ short lds[1024];
    for (int i = tid; i < 1024; i += 512) lds[i] = 0;

    // --- W fragments: B-operand layout, lane holds W[n=.., k=quad*8+j] ---
    short8 wh[2][8], wl[2][8];
#pragma unroll
    for (int tile = 0; tile < 2; ++tile) {
        const int n = wave * 32 + tile * 16 + lcol;
        const float* wr = Whh + (size_t)n * D_DIM + quad * 8;
#pragma unroll
        for (int kt = 0; kt < 8; ++kt) {
            float4 x0 = *(const float4*)(wr + kt * 32);
            float4 x1 = *(const float4*)(wr + kt * 32 + 4);
            float xs[8] = {x0.x, x0.y, x0.z, x0.w, x1.x, x1.y, x1.z, x1.w};
            short8 hi8, lo8;
#pragma unroll
            for (int j = 0; j < 8; ++j) {
                unsigned short h = f2bf(xs[j]);
                unsigned short l = f2bf(xs[j] - bf2f(h));
                hi8[j] = (short)h;
                lo8[j] = (short)l;
            }
            wh[tile][kt] = hi8;
            wl[tile][kt] = lo8;
        }
    }

    const bool active = (lane < 16);           // quad==0 holds C rows 0..3
    const int n0 = wave * 32 + lcol;           // tile 0 unit
    const int n1 = n0 + 16;                    // tile 1 unit
    const size_t rowbase = (size_t)b * T_DIM * D_DIM;

    // Persistent packed A fragment: row 0 (lanes lcol==0) = h_hi chunk,
    // row 1 (lanes lcol==1) = h_lo chunk, rows 2..15 permanently zero.
    const short8 ZS = {0, 0, 0, 0, 0, 0, 0, 0};
    short8 aP[8];
#pragma unroll
    for (int kt = 0; kt < 8; ++kt) aP[kt] = ZS;

    const int aq = quad * 8;                   // k-chunk within buffer

    // 2-step-deep pre pipeline: pv = step t, nv = step t+1
    float pv0 = 0.f, pv1 = 0.f, nv0 = 0.f, nv1 = 0.f;
    if (active) {
        pv0 = pre[rowbase + n0];
        pv1 = pre[rowbase + n1];
        nv0 = pre[rowbase + D_DIM + n0];
        nv1 = pre[rowbase + D_DIM + n1];
    }
    lds_barrier();

    const f32x4 Z = {0.f, 0.f, 0.f, 0.f};

    for (int t = 0; t < T_DIM; ++t) {
        // prefetch step t+2's pre
        float qv0 = 0.f, qv1 = 0.f;
        if (active && t + 2 < T_DIM) {
            const float* p2 = pre + rowbase + (size_t)(t + 2) * D_DIM;
            qv0 = p2[n0];
            qv1 = p2[n1];
        }

        // exec-masked A loads: lanes lcol==0 read h_hi, lcol==1 read h_lo
        const int bh = (t & 1) ? 512 : 0;
        if (lcol < 2) {
            const short* pa = lds + bh + lcol * 256 + aq;
#pragma unroll
            for (int kt = 0; kt < 8; ++kt)
                aP[kt] = *(const short8*)(pa + kt * 32);
        }

        // 4 chains: a1* (B=wh: row0=hh, row1=lh), a2* (B=wl: row0=hl)
        f32x4 a1t0, a1t1, a2t0, a2t1;
        a1t0 = __builtin_amdgcn_mfma_f32_16x16x32_bf16(aP[0], wh[0][0], Z, 0, 0, 0);
        a1t1 = __builtin_amdgcn_mfma_f32_16x16x32_bf16(aP[0], wh[1][0], Z, 0, 0, 0);
        a2t0 = __builtin_amdgcn_mfma_f32_16x16x32_bf16(aP[0], wl[0][0], Z, 0, 0, 0);
        a2t1 = __builtin_amdgcn_mfma_f32_16x16x32_bf16(aP[0], wl[1][0], Z, 0, 0, 0);
#pragma unroll
        for (int kt = 1; kt < 8; ++kt) {
            a1t0 = __builtin_amdgcn_mfma_f32_16x16x32_bf16(aP[kt], wh[0][kt], a1t0, 0, 0, 0);
            a1t1 = __builtin_amdgcn_mfma_f32_16x16x32_bf16(aP[kt], wh[1][kt], a1t1, 0, 0, 0);
            a2t0 = __builtin_amdgcn_mfma_f32_16x16x32_bf16(aP[kt], wl[0][kt], a2t0, 0, 0, 0);
            a2t1 = __builtin_amdgcn_mfma_f32_16x16x32_bf16(aP[kt], wl[1][kt], a2t1, 0, 0, 0);
        }

        // epilogue: lanes 0..15 hold C rows 0 (reg 0: hh/hl) and 1 (reg 1: lh)
        if (active) {
            const int wH = (t & 1) ? 0 : 512;   // write the other buffer
            float x0 = a1t0[0] + a1t0[1] + a2t0[0] + pv0;
            float x1 = a1t1[0] + a1t1[1] + a2t1[0] + pv1;
            float h0 = fast_tanh(x0);
            float h1 = fast_tanh(x1);
            hout[rowbase + (size_t)t * D_DIM + n0] = h0;   // stays in flight
            hout[rowbase + (size_t)t * D_DIM + n1] = h1;
            unsigned short h0h = f2bf(h0);
            unsigned short h0l = f2bf(h0 - bf2f(h0h));
            unsigned short h1h = f2bf(h1);
            unsigned short h1l = f2bf(h1 - bf2f(h1h));
            lds[wH + n0]       = (short)h0h;
            lds[wH + n1]       = (short)h1h;
            lds[wH + 256 + n0] = (short)h0l;
            lds[wH + 256 + n1] = (short)h1l;
        }
        pv0 = nv0; pv1 = nv1;
        nv0 = qv0; nv1 = qv1;
        lds_barrier();
    }
}

extern "C" void kernel_launch(void* const* d_in, const int* in_sizes, int n_in,
                              void* d_out, int out_size, void* d_ws, size_t ws_size,
                              hipStream_t stream)
{
    const int*   ids    = (const int*)  d_in[0];
    const float* emb    = (const float*)d_in[1];
    const float* W_ih0  = (const float*)d_in[2];
    const float* W_hh0  = (const float*)d_in[3];
    const float* b_ih0  = (const float*)d_in[4];
    const float* b_hh0  = (const float*)d_in[5];
    const float* W_ih1  = (const float*)d_in[6];
    const float* W_hh1  = (const float*)d_in[7];
    const float* b_ih1  = (const float*)d_in[8];
    const float* b_hh1  = (const float*)d_in[9];
    const float* W_head = (const float*)d_in[10];

    float* out = (float*)d_out;
    const int M = B_DIM * T_DIM;              // 65536
    float* pre0 = out;                        // d_out doubles as scratch
    float* pre1 = out + (size_t)M * D_DIM;
    float* h1   = (float*)d_ws;               // 64 MB of ws
    float* h2   = h1;

    // pre0 = emb[ids] @ W_ih0^T + (b_ih0 + b_hh0)
    gemm_bt_mfma<<<dim3(M / 128, D_DIM / 128), dim3(256), 0, stream>>>(
        nullptr, W_ih0, pre0, b_ih0, b_hh0, ids, emb, M, D_DIM, D_DIM);
    // layer-0 recurrence (MFMA, A-row-packed split-bf16, 1 batch row/block)
    rnn_scan_mfma<<<dim3(B_DIM), dim3(512), 0, stream>>>(pre0, W_hh0, h1);
    // pre1 = h1 @ W_ih1^T + (b_ih1 + b_hh1)
    gemm_bt_mfma<<<dim3(M / 128, D_DIM / 128), dim3(256), 0, stream>>>(
        h1, W_ih1, pre1, b_ih1, b_hh1, nullptr, nullptr, M, D_DIM, D_DIM);
    // layer-1 recurrence
    rnn_scan_mfma<<<dim3(B_DIM), dim3(512), 0, stream>>>(pre1, W_hh1, h2);
    // logits = h2 @ W_head^T
    gemm_bt_mfma<<<dim3(M / 128, S_DIM / 128), dim3(256), 0, stream>>>(
        h2, W_head, out, nullptr, nullptr, nullptr, nullptr, M, S_DIM, D_DIM);
}